// Round 1
// baseline (101.414 us; speedup 1.0000x reference)
//
#include <hip/hip_runtime.h>

#define BB   128          // batch
#define NN   1024         // vocab / matrix dim
#define RPB  16           // blocks per batch in quad kernel
#define ROWS (NN / RPB)   // 64 rows of K per block

// ---------------------------------------------------------------------------
// Kernel A: per-batch softmax + cross-entropy.  1 block (256 thr) per batch.
// Each thread owns 4 contiguous elements (float4).
// ---------------------------------------------------------------------------
__global__ __launch_bounds__(256) void softmax_ce_kernel(
    const float* __restrict__ m, const int* __restrict__ targets,
    float* __restrict__ p, float* __restrict__ ce)
{
    const int b   = blockIdx.x;
    const int tid = threadIdx.x;
    const float* mb = m + (size_t)b * NN;

    float4 v = reinterpret_cast<const float4*>(mb)[tid];

    __shared__ float sred[4];

    // ---- block max ----
    float mx = fmaxf(fmaxf(v.x, v.y), fmaxf(v.z, v.w));
    #pragma unroll
    for (int off = 32; off > 0; off >>= 1) mx = fmaxf(mx, __shfl_down(mx, off));
    if ((tid & 63) == 0) sred[tid >> 6] = mx;
    __syncthreads();
    mx = fmaxf(fmaxf(sred[0], sred[1]), fmaxf(sred[2], sred[3]));
    __syncthreads();   // protect sred before reuse

    // ---- block sum of exp ----
    float e0 = expf(v.x - mx), e1 = expf(v.y - mx);
    float e2 = expf(v.z - mx), e3 = expf(v.w - mx);
    float s = (e0 + e1) + (e2 + e3);
    #pragma unroll
    for (int off = 32; off > 0; off >>= 1) s += __shfl_down(s, off);
    if ((tid & 63) == 0) sred[tid >> 6] = s;
    __syncthreads();
    s = (sred[0] + sred[1]) + (sred[2] + sred[3]);

    const float inv = 1.0f / s;
    float4 pv = make_float4(e0 * inv, e1 * inv, e2 * inv, e3 * inv);
    reinterpret_cast<float4*>(p + (size_t)b * NN)[tid] = pv;

    if (tid == 0) {
        const float lse = mx + logf(s);
        ce[b] = lse - mb[targets[b]];
    }
}

// ---------------------------------------------------------------------------
// Kernel B: partial[blk] = sum over 64 rows of  k[n,m] * p[n] * (d(n,m)-p[m])
// Thread t owns columns [4t,4t+4); p[m] for those columns lives in registers,
// p[n] comes from LDS broadcast.  Fully coalesced float4 streaming of K.
// ---------------------------------------------------------------------------
__global__ __launch_bounds__(256) void quad_kernel(
    const float* __restrict__ k, const float* __restrict__ p,
    float* __restrict__ partial)
{
    const int blk = blockIdx.x;
    const int b   = blk / RPB;
    const int rb  = blk % RPB;
    const int tid = threadIdx.x;

    __shared__ float sp[NN];
    reinterpret_cast<float4*>(sp)[tid] =
        reinterpret_cast<const float4*>(p + (size_t)b * NN)[tid];
    __syncthreads();

    const int   m0  = 4 * tid;
    const float pm0 = sp[m0], pm1 = sp[m0 + 1], pm2 = sp[m0 + 2], pm3 = sp[m0 + 3];

    const int n0 = rb * ROWS;
    const float4* kp =
        reinterpret_cast<const float4*>(k + ((size_t)b * NN + n0) * NN) + tid;

    float acc = 0.0f;
    #pragma unroll 4
    for (int i = 0; i < ROWS; ++i) {
        const int n  = n0 + i;
        float4 k4    = kp[(size_t)i * (NN / 4)];
        float  pn    = sp[n];
        float  d0 = (n == m0    ) ? 1.0f : 0.0f;
        float  d1 = (n == m0 + 1) ? 1.0f : 0.0f;
        float  d2 = (n == m0 + 2) ? 1.0f : 0.0f;
        float  d3 = (n == m0 + 3) ? 1.0f : 0.0f;
        acc += pn * (k4.x * (d0 - pm0) + k4.y * (d1 - pm1) +
                     k4.z * (d2 - pm2) + k4.w * (d3 - pm3));
    }

    // ---- block reduce (wave64 shuffle, then cross-wave via LDS) ----
    #pragma unroll
    for (int off = 32; off > 0; off >>= 1) acc += __shfl_down(acc, off);
    __shared__ float sred[4];
    if ((tid & 63) == 0) sred[tid >> 6] = acc;
    __syncthreads();
    if (tid == 0) partial[blk] = (sred[0] + sred[1]) + (sred[2] + sred[3]);
}

// ---------------------------------------------------------------------------
// Kernel C: out[b] = ce[b] + 0.5 * sum_r partial[b*RPB + r]
// ---------------------------------------------------------------------------
__global__ void finalize_kernel(const float* __restrict__ ce,
                                const float* __restrict__ partial,
                                float* __restrict__ out)
{
    const int b = threadIdx.x;
    if (b < BB) {
        float s = 0.0f;
        #pragma unroll
        for (int r = 0; r < RPB; ++r) s += partial[b * RPB + r];
        out[b] = ce[b] + 0.5f * s;
    }
}

// ---------------------------------------------------------------------------
extern "C" void kernel_launch(void* const* d_in, const int* in_sizes, int n_in,
                              void* d_out, int out_size, void* d_ws, size_t ws_size,
                              hipStream_t stream)
{
    const float* m       = (const float*)d_in[0];
    const float* k       = (const float*)d_in[1];
    const int*   targets = (const int*)d_in[2];
    float*       out     = (float*)d_out;

    // workspace layout: p[B*N] | ce[B] | partial[B*RPB]
    float* p       = (float*)d_ws;
    float* ce      = p + (size_t)BB * NN;
    float* partial = ce + BB;

    softmax_ce_kernel<<<BB, 256, 0, stream>>>(m, targets, p, ce);
    quad_kernel<<<BB * RPB, 256, 0, stream>>>(k, p, partial);
    finalize_kernel<<<1, 128, 0, stream>>>(ce, partial, out);
}

// Round 2
// 85.219 us; speedup vs baseline: 1.1900x; 1.1900x over previous
//
#include <hip/hip_runtime.h>

#define BB   128          // batch
#define NN   1024         // vocab / matrix dim
#define RPB  16           // blocks per batch
#define ROWS (NN / RPB)   // 64 rows of K per block

typedef float f4 __attribute__((ext_vector_type(4)));

// ---------------------------------------------------------------------------
// Fused kernel: each block (b, rb) recomputes softmax(m[b]) from scratch
// (m[b] is 4 KB — L2/L3-resident across the 16 blocks of a batch), then
// streams its 64-row slice of K accumulating
//     sum_{n,m} k[n,m] * p[n] * (delta(n,m) - p[m]).
// Block rb==0 additionally writes ce[b].  No global p buffer at all.
// ---------------------------------------------------------------------------
__global__ __launch_bounds__(256) void fused_quad_kernel(
    const float* __restrict__ m, const float* __restrict__ k,
    const int* __restrict__ targets,
    float* __restrict__ ce, float* __restrict__ partial)
{
    const int blk = blockIdx.x;
    const int b   = blk >> 4;        // blk / RPB
    const int rb  = blk & (RPB - 1); // blk % RPB
    const int tid = threadIdx.x;

    __shared__ float sp[NN];
    __shared__ float sred[4];

    // ---- softmax over m[b] (each thread owns 4 contiguous elements) ----
    const float* mb = m + (size_t)b * NN;
    float4 v = reinterpret_cast<const float4*>(mb)[tid];

    float mx = fmaxf(fmaxf(v.x, v.y), fmaxf(v.z, v.w));
    #pragma unroll
    for (int off = 32; off > 0; off >>= 1) mx = fmaxf(mx, __shfl_down(mx, off));
    if ((tid & 63) == 0) sred[tid >> 6] = mx;
    __syncthreads();
    mx = fmaxf(fmaxf(sred[0], sred[1]), fmaxf(sred[2], sred[3]));
    __syncthreads();

    float e0 = expf(v.x - mx), e1 = expf(v.y - mx);
    float e2 = expf(v.z - mx), e3 = expf(v.w - mx);
    float s = (e0 + e1) + (e2 + e3);
    #pragma unroll
    for (int off = 32; off > 0; off >>= 1) s += __shfl_down(s, off);
    if ((tid & 63) == 0) sred[tid >> 6] = s;
    __syncthreads();
    s = (sred[0] + sred[1]) + (sred[2] + sred[3]);

    const float inv = 1.0f / s;
    const float pm0 = e0 * inv, pm1 = e1 * inv, pm2 = e2 * inv, pm3 = e3 * inv;
    reinterpret_cast<float4*>(sp)[tid] = make_float4(pm0, pm1, pm2, pm3);
    __syncthreads();

    if (rb == 0 && tid == 0)
        ce[b] = mx + logf(s) - mb[targets[b]];

    // ---- stream 64 rows of K ----
    const int m0 = 4 * tid;
    const int n0 = rb * ROWS;
    const f4* kp = reinterpret_cast<const f4*>(k + ((size_t)b * NN + n0) * NN) + tid;

    float acc = 0.0f;
    #pragma unroll 8
    for (int i = 0; i < ROWS; ++i) {
        const int n = n0 + i;
        f4    k4 = __builtin_nontemporal_load(kp + (size_t)i * (NN / 4));
        float pn = sp[n];
        float d0 = (n == m0    ) ? 1.0f : 0.0f;
        float d1 = (n == m0 + 1) ? 1.0f : 0.0f;
        float d2 = (n == m0 + 2) ? 1.0f : 0.0f;
        float d3 = (n == m0 + 3) ? 1.0f : 0.0f;
        acc += pn * (k4.x * (d0 - pm0) + k4.y * (d1 - pm1) +
                     k4.z * (d2 - pm2) + k4.w * (d3 - pm3));
    }

    // ---- block reduce ----
    #pragma unroll
    for (int off = 32; off > 0; off >>= 1) acc += __shfl_down(acc, off);
    __syncthreads();   // sred reuse safety
    if ((tid & 63) == 0) sred[tid >> 6] = acc;
    __syncthreads();
    if (tid == 0) partial[blk] = (sred[0] + sred[1]) + (sred[2] + sred[3]);
}

// ---------------------------------------------------------------------------
// out[b] = ce[b] + 0.5 * sum_r partial[b*RPB + r]
// ---------------------------------------------------------------------------
__global__ void finalize_kernel(const float* __restrict__ ce,
                                const float* __restrict__ partial,
                                float* __restrict__ out)
{
    const int b = threadIdx.x;
    if (b < BB) {
        float s = 0.0f;
        #pragma unroll
        for (int r = 0; r < RPB; ++r) s += partial[b * RPB + r];
        out[b] = ce[b] + 0.5f * s;
    }
}

// ---------------------------------------------------------------------------
extern "C" void kernel_launch(void* const* d_in, const int* in_sizes, int n_in,
                              void* d_out, int out_size, void* d_ws, size_t ws_size,
                              hipStream_t stream)
{
    const float* m       = (const float*)d_in[0];
    const float* k       = (const float*)d_in[1];
    const int*   targets = (const int*)d_in[2];
    float*       out     = (float*)d_out;

    // workspace layout: ce[B] | partial[B*RPB]
    float* ce      = (float*)d_ws;
    float* partial = ce + BB;

    fused_quad_kernel<<<BB * RPB, 256, 0, stream>>>(m, k, targets, ce, partial);
    finalize_kernel<<<1, 128, 0, stream>>>(ce, partial, out);
}